// Round 5
// baseline (251.744 us; speedup 1.0000x reference)
//
#include <hip/hip_runtime.h>
#include <hip/hip_bf16.h>

#define NB 31
#define PD 64

typedef __attribute__((ext_vector_type(8))) short short8;
typedef __attribute__((ext_vector_type(16))) float f32x16;

// 0-transcendental GELU: x * clamp(0.5 + x*(a + b x^2 + c x^4), 0, 1)
__device__ __forceinline__ float gelu_f(float x) {
    float y = x * x;
    float p = __builtin_fmaf(y, __builtin_fmaf(y, 0.0042294f, -0.056913f), 0.395442f);
    float phi = __builtin_fmaf(x, p, 0.5f);
    phi = __builtin_fmaxf(0.0f, __builtin_fminf(phi, 1.0f));
    return x * phi;
}

__device__ __forceinline__ unsigned int cvt_pk_bf16(float lo, float hi) {
    unsigned int r;
    asm("v_cvt_pk_bf16_f32 %0, %1, %2" : "=v"(r) : "v"(lo), "v"(hi));
    return r;
}

__device__ __forceinline__ unsigned short f2bf(float f) {
    unsigned int u = __float_as_uint(f);
    unsigned int r = (u + 0x7FFFu + ((u >> 16) & 1u)) >> 16;
    return (unsigned short)r;
}

// Reorder W2 (OIHW, fp32) -> MFMA A-fragment order (bf16):
// W2r[g][oh][kk][lane][j], oc = oh*32 + (lane&31), tap = kk>>2,
// ic = (kk&3)*16 + (lane>>5)*8 + j
__global__ void prep_w2(const float* __restrict__ W2, unsigned short* __restrict__ W2r) {
    int e = blockIdx.x * 256 + threadIdx.x;
    const int TOT = NB * 2 * 36 * 512;
    if (e >= TOT) return;
    int j  = e & 7;
    int l  = (e >> 3) & 63;
    int kk = (e >> 9) % 36;
    int gh = e / (36 * 512);
    int g  = gh >> 1, oh = gh & 1;
    int oc  = oh * 32 + (l & 31);
    int ic  = (kk & 3) * 16 + ((l >> 5) << 3) + j;
    int tap = kk >> 2;
    float v = W2[((g * 64 + oc) * 64 + ic) * 9 + tap];
    W2r[e] = f2bf(v);
}

// One block: (batch n, band g, 16x16 output tile). 256 threads = 4 waves.
// conv1 AND conv2 both via mfma_32x32x16_bf16; LDS holds only xs + h1.
__global__ __launch_bounds__(256, 3) void band_kernel(
    const float* __restrict__ x, const float* __restrict__ W1, const float* __restrict__ b1,
    const float* __restrict__ b2, const float* __restrict__ W3, const float* __restrict__ b3,
    const unsigned short* __restrict__ W2r, float* __restrict__ out)
{
    __shared__ float  xs[20 * 20];
    __shared__ short8 h1s8[384 * 8];   // 49152 B: [pos][64 ic] bf16, slot-swizzled; 324 real + pad

    const int tid = threadIdx.x;
    const int tx = blockIdx.x % 12, ty = blockIdx.x / 12;
    const int g = blockIdx.y, n = blockIdx.z;
    const int x0 = tx * 16, y0 = ty * 16;

    const int lane = tid & 63;
    const int w    = tid >> 6;
    const int hi   = lane >> 5;     // k-half for MFMA operands
    const int col  = lane & 31;

    // ---- stage x tile (20x20, halo 2, zero-padded) ----
    const float* xg = x + (size_t)(n * NB + g) * 192 * 192;
    for (int i = tid; i < 400; i += 256) {
        int r = i / 20, c = i - r * 20;
        int gy = y0 + r - 2, gx = x0 + c - 2;
        float v = 0.f;
        if (gy >= 0 && gy < 192 && gx >= 0 && gx < 192) v = xg[gy * 192 + gx];
        xs[i] = v;
    }

    // ---- conv1 A-frags from W1 (global, L1-cached): A[oc][k=tap], taps 9..15 = 0
    short8 a1[2];
#pragma unroll
    for (int oh = 0; oh < 2; ++oh) {
        const float* wp = W1 + (size_t)(g * 64 + oh * 32 + col) * 9;
        uint4 bw = {0u, 0u, 0u, 0u};
        if (hi == 0) {
            bw.x = cvt_pk_bf16(wp[0], wp[1]);
            bw.y = cvt_pk_bf16(wp[2], wp[3]);
            bw.z = cvt_pk_bf16(wp[4], wp[5]);
            bw.w = cvt_pk_bf16(wp[6], wp[7]);
        } else {
            bw.x = cvt_pk_bf16(wp[8], 0.f);
        }
        a1[oh] = __builtin_bit_cast(short8, bw);
    }
    // ---- b1 into regs: b1r[oh*16 + 4s + j] = b1[g*64 + oh*32 + 8s + 4hi + j]
    float b1r[32];
    {
        const float* bp = b1 + g * 64 + 4 * hi;
#pragma unroll
        for (int oh = 0; oh < 2; ++oh)
#pragma unroll
            for (int s = 0; s < 4; ++s) {
                float4 q = *(const float4*)(bp + oh * 32 + 8 * s);
                b1r[oh * 16 + 4 * s + 0] = q.x;
                b1r[oh * 16 + 4 * s + 1] = q.y;
                b1r[oh * 16 + 4 * s + 2] = q.z;
                b1r[oh * 16 + 4 * s + 3] = q.w;
            }
    }
    __syncthreads();   // xs ready

    // ---- conv1 via MFMA: 12 tiles of 32 positions (324 real, rest pad) ----
    char* h1c = (char*)h1s8;
#pragma unroll
    for (int it = 0; it < 3; ++it) {
        const int t = w + 4 * it;
        const int pos = t * 32 + col;
        int py = pos / 18, px = pos - py * 18;   // halo coords (pad tiles: OOB but unread)
        int gy = y0 + py - 1, gx = x0 + px - 1;
        unsigned int msk = (gy >= 0 && gy < 192 && gx >= 0 && gx < 192) ? 0xFFFFFFFFu : 0u;

        // B frag: B[k=tap][col=pos]; lanes<32: taps 0..7, lanes>=32: tap 8 + zeros
        uint4 bw = {0u, 0u, 0u, 0u};
        if (hi == 0) {
            float xv[8];
#pragma unroll
            for (int j2 = 0; j2 < 8; ++j2)
                xv[j2] = xs[(py + j2 / 3) * 20 + px + (j2 % 3)];
            bw.x = cvt_pk_bf16(xv[0], xv[1]);
            bw.y = cvt_pk_bf16(xv[2], xv[3]);
            bw.z = cvt_pk_bf16(xv[4], xv[5]);
            bw.w = cvt_pk_bf16(xv[6], xv[7]);
        } else {
            bw.x = cvt_pk_bf16(xs[(py + 2) * 20 + px + 2], 0.f);
        }
        short8 bfrag = __builtin_bit_cast(short8, bw);

        f32x16 z = {};
        f32x16 c0 = __builtin_amdgcn_mfma_f32_32x32x16_bf16(a1[0], bfrag, z, 0, 0, 0);
        f32x16 c1 = __builtin_amdgcn_mfma_f32_32x32x16_bf16(a1[1], bfrag, z, 0, 0, 0);

        // epilogue: gelu, pack, permlane-swap so every lane stores a full 16B chunk.
        // lane<32 stores oh=0 chunk s; lane>=32 stores oh=1 chunk s (chunk = 4*oh_eff+s).
        const int pbase = pos << 7;
#pragma unroll
        for (int s = 0; s < 4; ++s) {
            float u00 = gelu_f(c0[4 * s + 0] + b1r[4 * s + 0]);
            float u01 = gelu_f(c0[4 * s + 1] + b1r[4 * s + 1]);
            float u02 = gelu_f(c0[4 * s + 2] + b1r[4 * s + 2]);
            float u03 = gelu_f(c0[4 * s + 3] + b1r[4 * s + 3]);
            float u10 = gelu_f(c1[4 * s + 0] + b1r[16 + 4 * s + 0]);
            float u11 = gelu_f(c1[4 * s + 1] + b1r[16 + 4 * s + 1]);
            float u12 = gelu_f(c1[4 * s + 2] + b1r[16 + 4 * s + 2]);
            float u13 = gelu_f(c1[4 * s + 3] + b1r[16 + 4 * s + 3]);
            unsigned int W0x = cvt_pk_bf16(u00, u01) & msk;
            unsigned int W0y = cvt_pk_bf16(u02, u03) & msk;
            unsigned int W1x = cvt_pk_bf16(u10, u11) & msk;
            unsigned int W1y = cvt_pk_bf16(u12, u13) & msk;
            // swap: W1*[0:31] <- W0*[32:63];  W0*[32:63] <- W1*[0:31]
            asm volatile("v_permlane32_swap_b32 %0, %1" : "+v"(W1x), "+v"(W0x));
            asm volatile("v_permlane32_swap_b32 %0, %1" : "+v"(W1y), "+v"(W0y));
            uint4 st = {W0x, W0y, W1x, W1y};
            int slot = (pos & 7) ^ (hi * 4 + s);
            *(uint4*)(h1c + pbase + (slot << 4)) = st;
        }
    }
    __syncthreads();

    // ---- conv2 via MFMA: wave w = px rows [4w,4w+4), both oc-halves ----
    const int lq    = hi;
    const int lhalf = (lane >> 4) & 1;
    const int pxl   = lane & 15;
    const int lq4   = lq << 4;

    const int baseNT0 = (w * 4 + lhalf) * 18 + pxl;
    const int baseNT1 = baseNT0 + 36;

    const short8* a0p = (const short8*)W2r + (size_t)(g * 2) * 36 * 64 + lane;
    const short8* a1p = a0p + 36 * 64;

    f32x16 acc00 = {}, acc10 = {}, acc01 = {}, acc11 = {};
    short8 A0[4], A1[4];
    A0[0] = a0p[0];   A1[0] = a1p[0];
    A0[1] = a0p[64];  A1[1] = a1p[64];
    A0[2] = a0p[128]; A1[2] = a1p[128];

#pragma unroll
    for (int tap = 0; tap < 9; ++tap) {
        const int D = (tap / 3) * 18 + (tap % 3);
        int p0 = baseNT0 + D;
        int p1 = baseNT1 + D;
        int ad0 = (p0 << 7) + ((((p0 & 7) << 4)) ^ lq4);
        int ad1 = (p1 << 7) + ((((p1 & 7) << 4)) ^ lq4);
#pragma unroll
        for (int q = 0; q < 4; ++q) {
            const int kk = tap * 4 + q;
            if (kk + 3 < 36) {
                A0[(kk + 3) & 3] = a0p[(kk + 3) * 64];
                A1[(kk + 3) & 3] = a1p[(kk + 3) * 64];
            }
            short8 bf0 = *(const short8*)(h1c + (ad0 ^ (q << 5)));
            short8 bf1v = *(const short8*)(h1c + (ad1 ^ (q << 5)));
            acc00 = __builtin_amdgcn_mfma_f32_32x32x16_bf16(A0[kk & 3], bf0,  acc00, 0, 0, 0);
            acc10 = __builtin_amdgcn_mfma_f32_32x32x16_bf16(A1[kk & 3], bf0,  acc10, 0, 0, 0);
            acc01 = __builtin_amdgcn_mfma_f32_32x32x16_bf16(A0[kk & 3], bf1v, acc01, 0, 0, 0);
            acc11 = __builtin_amdgcn_mfma_f32_32x32x16_bf16(A1[kk & 3], bf1v, acc11, 0, 0, 0);
        }
    }

    // ---- epilogue: W3/b2 to regs (global, L1), gelu, conv3 dot, reduce, store
    float w3r[32], b2r[32];
    {
        const float* wp = W3 + g * 64 + 4 * lq;
        const float* bp = b2 + g * 64 + 4 * lq;
#pragma unroll
        for (int oh = 0; oh < 2; ++oh)
#pragma unroll
            for (int s = 0; s < 4; ++s) {
                float4 qa = *(const float4*)(wp + oh * 32 + 8 * s);
                float4 qb = *(const float4*)(bp + oh * 32 + 8 * s);
                w3r[oh * 16 + 4 * s + 0] = qa.x; w3r[oh * 16 + 4 * s + 1] = qa.y;
                w3r[oh * 16 + 4 * s + 2] = qa.z; w3r[oh * 16 + 4 * s + 3] = qa.w;
                b2r[oh * 16 + 4 * s + 0] = qb.x; b2r[oh * 16 + 4 * s + 1] = qb.y;
                b2r[oh * 16 + 4 * s + 2] = qb.z; b2r[oh * 16 + 4 * s + 3] = qb.w;
            }
    }
    const float b3g = b3[g];
    float* outg = out + ((size_t)(n * NB + g) * 192 + y0) * 192 + x0;
#define EPI(ACC_O0, ACC_O1, NT)                                               \
    {                                                                         \
        float p = 0.f;                                                        \
        _Pragma("unroll")                                                     \
        for (int r = 0; r < 16; ++r) {                                        \
            p += w3r[r]      * gelu_f(ACC_O0[r] + b2r[r]);                    \
            p += w3r[16 + r] * gelu_f(ACC_O1[r] + b2r[16 + r]);               \
        }                                                                     \
        p += __shfl_xor(p, 32);                                               \
        if (lane < 32) {                                                      \
            int py = w * 4 + (NT) * 2 + (lane >> 4);                          \
            outg[py * 192 + (lane & 15)] = p + b3g;                           \
        }                                                                     \
    }
    EPI(acc00, acc10, 0)
    EPI(acc01, acc11, 1)
#undef EPI
}

// Cross-band fusion, in-place on `out`. Weight indices are wave-uniform ->
// compiler emits s_load (K$/L2), no LDS staging needed.
__global__ __launch_bounds__(256) void fuse_kernel(
    const float* __restrict__ x,
    const float* __restrict__ Wf1, const float* __restrict__ bf1,
    const float* __restrict__ Wf2, const float* __restrict__ bf2,
    float* __restrict__ out)
{
    const int tid = threadIdx.x;
    int p = blockIdx.x * 256 + tid;          // 0..73727
    int nn = p / 36864, pix = p - nn * 36864;
    float* basep = out + (size_t)nn * NB * 36864 + pix;
    const float* xb = x + (size_t)nn * NB * 36864 + pix;

    float v[31];
#pragma unroll
    for (int c = 0; c < 31; ++c) v[c] = basep[(size_t)c * 36864];

    float fused[31];
#pragma unroll
    for (int c = 0; c < 31; ++c) fused[c] = bf2[c];

#pragma unroll 2
    for (int j = 0; j < 62; ++j) {
        float a = bf1[j];
#pragma unroll
        for (int c = 0; c < 31; ++c) a = __builtin_fmaf(Wf1[j * 31 + c], v[c], a);
        float fj = gelu_f(a);
#pragma unroll
        for (int c = 0; c < 31; ++c) fused[c] = __builtin_fmaf(Wf2[c * 62 + j], fj, fused[c]);
    }
#pragma unroll
    for (int c = 0; c < 31; ++c) basep[(size_t)c * 36864] = xb[(size_t)c * 36864] + fused[c];
}

extern "C" void kernel_launch(void* const* d_in, const int* in_sizes, int n_in,
                              void* d_out, int out_size, void* d_ws, size_t ws_size,
                              hipStream_t stream) {
    const float* x   = (const float*)d_in[0];
    const float* W1  = (const float*)d_in[1];
    const float* b1  = (const float*)d_in[2];
    const float* W2  = (const float*)d_in[3];
    const float* b2  = (const float*)d_in[4];
    const float* W3  = (const float*)d_in[5];
    const float* b3  = (const float*)d_in[6];
    const float* Wf1 = (const float*)d_in[7];
    const float* bf1 = (const float*)d_in[8];
    const float* Wf2 = (const float*)d_in[9];
    const float* bf2 = (const float*)d_in[10];
    float* out = (float*)d_out;
    unsigned short* W2r = (unsigned short*)d_ws;   // 1142784 bf16 = 2.29 MB

    const int TOT = NB * 2 * 36 * 512;
    hipLaunchKernelGGL(prep_w2, dim3((TOT + 255) / 256), dim3(256), 0, stream, W2, W2r);
    hipLaunchKernelGGL(band_kernel, dim3(144, NB, 2), dim3(256), 0, stream,
                       x, W1, b1, b2, W3, b3, W2r, out);
    hipLaunchKernelGGL(fuse_kernel, dim3(288), dim3(256), 0, stream,
                       x, Wf1, bf1, Wf2, bf2, out);
}

// Round 8
// 226.377 us; speedup vs baseline: 1.1121x; 1.1121x over previous
//
#include <hip/hip_runtime.h>
#include <hip/hip_bf16.h>

#define NB 31
#define PD 64

typedef __attribute__((ext_vector_type(8))) short short8;
typedef __attribute__((ext_vector_type(16))) float f32x16;
typedef unsigned long long u64;

// 0-transcendental GELU: x * clamp(0.5 + x*(a + b x^2 + c x^4), 0, 1)
__device__ __forceinline__ float gelu_f(float x) {
    float y = x * x;
    float p = __builtin_fmaf(y, __builtin_fmaf(y, 0.0042294f, -0.056913f), 0.395442f);
    float phi = __builtin_fmaf(x, p, 0.5f);
    phi = __builtin_fmaxf(0.0f, __builtin_fminf(phi, 1.0f));
    return x * phi;
}

__device__ __forceinline__ unsigned int cvt_pk_bf16(float lo, float hi) {
    unsigned int r;
    asm("v_cvt_pk_bf16_f32 %0, %1, %2" : "=v"(r) : "v"(lo), "v"(hi));
    return r;
}

// 2 floats -> 2 fp8 e4m3 bytes in bits [15:0].  Basic form only (old=0,
// word=false); upper bits masked off defensively.
__device__ __forceinline__ unsigned int pk_fp8(float a, float b) {
    return (unsigned int)__builtin_amdgcn_cvt_pk_fp8_f32(a, b, 0, false) & 0xFFFFu;
}

// Reorder W2 (OIHW, fp32) -> fp8 e4m3 MFMA A-fragment order:
// W2r[g][oh][kk][lane] = 8 bytes, oc = oh*32 + (lane&31), tap = kk>>2,
// ic = (kk&3)*16 + (lane>>5)*8 + j  (k-global = ic + 64*tap)
__global__ void prep_w2(const float* __restrict__ W2, unsigned char* __restrict__ W2r) {
    int e = blockIdx.x * 256 + threadIdx.x;
    const int TOT = NB * 2 * 36 * 64;
    if (e >= TOT) return;
    int lane = e & 63;
    int kk = (e >> 6) % 36;
    int gh = e / (36 * 64);
    int g = gh >> 1, oh = gh & 1;
    int oc  = oh * 32 + (lane & 31);
    int icb = (kk & 3) * 16 + ((lane >> 5) << 3);
    int tap = kk >> 2;
    const float* wp = W2 + ((size_t)(g * 64 + oc) * 64 + icb) * 9 + tap;
    float f[8];
#pragma unroll
    for (int j = 0; j < 8; ++j) f[j] = wp[j * 9];
    uint2 st;
    st.x = pk_fp8(f[0], f[1]) | (pk_fp8(f[2], f[3]) << 16);
    st.y = pk_fp8(f[4], f[5]) | (pk_fp8(f[6], f[7]) << 16);
    ((uint2*)W2r)[e] = st;
}

// One block: (batch n, band g, 16x16 output tile). 256 threads = 4 waves.
// conv1 in bf16 MFMA (accuracy); h1 stored fp8 e4m3; conv2 via fp8 MFMA.
// LDS layout: row pos = 64B, 8 slots x 8B; ic-chunk c at slot c ^ X(pos),
// X = (pos&7) ^ ((pos>>3)&3).  Lane (col,hi) stores 4B halves directly.
__global__ __launch_bounds__(256, 4) void band_kernel(
    const float* __restrict__ x, const float* __restrict__ W1, const float* __restrict__ b1,
    const float* __restrict__ b2, const float* __restrict__ W3, const float* __restrict__ b3,
    const unsigned char* __restrict__ W2r, float* __restrict__ out)
{
    __shared__ float xs[20 * 20];
    __shared__ u64   h1s8[384 * 8];   // 24576 B

    const int tid = threadIdx.x;
    const int tx = blockIdx.x % 12, ty = blockIdx.x / 12;
    const int g = blockIdx.y, n = blockIdx.z;
    const int x0 = tx * 16, y0 = ty * 16;

    const int lane = tid & 63;
    const int w    = tid >> 6;
    const int hi   = lane >> 5;     // k-half for MFMA operands
    const int col  = lane & 31;

    // ---- stage x tile (20x20, halo 2, zero-padded) ----
    const float* xg = x + (size_t)(n * NB + g) * 192 * 192;
    for (int i = tid; i < 400; i += 256) {
        int r = i / 20, c = i - r * 20;
        int gy = y0 + r - 2, gx = x0 + c - 2;
        float v = 0.f;
        if (gy >= 0 && gy < 192 && gx >= 0 && gx < 192) v = xg[gy * 192 + gx];
        xs[i] = v;
    }

    // ---- conv1 A-frags from W1 (bf16): A[oc][k=tap], taps 9..15 = 0 ----
    short8 a1[2];
#pragma unroll
    for (int oh = 0; oh < 2; ++oh) {
        const float* wp = W1 + (size_t)(g * 64 + oh * 32 + col) * 9;
        uint4 bw = {0u, 0u, 0u, 0u};
        if (hi == 0) {
            bw.x = cvt_pk_bf16(wp[0], wp[1]);
            bw.y = cvt_pk_bf16(wp[2], wp[3]);
            bw.z = cvt_pk_bf16(wp[4], wp[5]);
            bw.w = cvt_pk_bf16(wp[6], wp[7]);
        } else {
            bw.x = cvt_pk_bf16(wp[8], 0.f);
        }
        a1[oh] = __builtin_bit_cast(short8, bw);
    }
    // ---- b1 into regs: b1r[oh*16 + 4s + j] = b1[g*64 + oh*32 + 8s + 4hi + j]
    float b1r[32];
    {
        const float* bp = b1 + g * 64 + 4 * hi;
#pragma unroll
        for (int oh = 0; oh < 2; ++oh)
#pragma unroll
            for (int s = 0; s < 4; ++s) {
                float4 q = *(const float4*)(bp + oh * 32 + 8 * s);
                b1r[oh * 16 + 4 * s + 0] = q.x;
                b1r[oh * 16 + 4 * s + 1] = q.y;
                b1r[oh * 16 + 4 * s + 2] = q.z;
                b1r[oh * 16 + 4 * s + 3] = q.w;
            }
    }
    __syncthreads();   // xs ready

    // ---- conv1 via MFMA: 12 tiles of 32 positions (324 real, rest pad) ----
    // Pad positions compute with pos clamped to 323 (in-bounds, finite) but
    // write to their own rows 324..383 (never read by conv2).
    char* h1c = (char*)h1s8;
#pragma unroll
    for (int it = 0; it < 3; ++it) {
        const int t = w + 4 * it;
        const int posr = t * 32 + col;             // write row 0..383
        const int pos  = posr < 324 ? posr : 323;  // compute position
        int py = pos / 18, px = pos - py * 18;     // halo coords 0..17
        int gy = y0 + py - 1, gx = x0 + px - 1;
        unsigned int msk = (gy >= 0 && gy < 192 && gx >= 0 && gx < 192) ? 0xFFFFFFFFu : 0u;

        // B frag: B[k=tap][col=pos]; lanes<32: taps 0..7, lanes>=32: tap 8 + zeros
        uint4 bw = {0u, 0u, 0u, 0u};
        if (hi == 0) {
            float xv[8];
#pragma unroll
            for (int j2 = 0; j2 < 8; ++j2)
                xv[j2] = xs[(py + j2 / 3) * 20 + px + (j2 % 3)];
            bw.x = cvt_pk_bf16(xv[0], xv[1]);
            bw.y = cvt_pk_bf16(xv[2], xv[3]);
            bw.z = cvt_pk_bf16(xv[4], xv[5]);
            bw.w = cvt_pk_bf16(xv[6], xv[7]);
        } else {
            bw.x = cvt_pk_bf16(xs[(py + 2) * 20 + px + 2], 0.f);
        }
        short8 bfrag = __builtin_bit_cast(short8, bw);

        f32x16 z = {};
        f32x16 c0 = __builtin_amdgcn_mfma_f32_32x32x16_bf16(a1[0], bfrag, z, 0, 0, 0);
        f32x16 c1 = __builtin_amdgcn_mfma_f32_32x32x16_bf16(a1[1], bfrag, z, 0, 0, 0);

        // gelu -> fp8 -> per-lane 4B stores (no cross-lane ops).
        // Lane (col,hi), acc reg 4s+j: oh0 -> ic 8s+4hi+j (chunk s, half hi);
        //                              oh1 -> ic 32+8s+4hi+j (chunk 4+s, half hi).
        const int X = (posr & 7) ^ ((posr >> 3) & 3);
        const int rowb = posr << 6;
        const int bsel = hi << 2;      // byte offset of this lane's half-chunk
#pragma unroll
        for (int s = 0; s < 4; ++s) {
            float u00 = gelu_f(c0[4 * s + 0] + b1r[4 * s + 0]);
            float u01 = gelu_f(c0[4 * s + 1] + b1r[4 * s + 1]);
            float u02 = gelu_f(c0[4 * s + 2] + b1r[4 * s + 2]);
            float u03 = gelu_f(c0[4 * s + 3] + b1r[4 * s + 3]);
            float u10 = gelu_f(c1[4 * s + 0] + b1r[16 + 4 * s + 0]);
            float u11 = gelu_f(c1[4 * s + 1] + b1r[16 + 4 * s + 1]);
            float u12 = gelu_f(c1[4 * s + 2] + b1r[16 + 4 * s + 2]);
            float u13 = gelu_f(c1[4 * s + 3] + b1r[16 + 4 * s + 3]);
            unsigned int E0 = (pk_fp8(u00, u01) | (pk_fp8(u02, u03) << 16)) & msk;
            unsigned int E1 = (pk_fp8(u10, u11) | (pk_fp8(u12, u13) << 16)) & msk;
            *(unsigned int*)(h1c + rowb + (((s ^ X) << 3) | bsel))       = E0;
            *(unsigned int*)(h1c + rowb + ((((4 + s) ^ X) << 3) | bsel)) = E1;
        }
    }
    __syncthreads();

    // ---- conv2 via fp8 MFMA: wave w = px rows [4w,4w+4), both oc-halves ----
    const int lhalf = (lane >> 4) & 1;
    const int pxl   = lane & 15;

    const int baseNT0 = (w * 4 + lhalf) * 18 + pxl;
    const int baseNT1 = baseNT0 + 36;

    const u64* a0p = (const u64*)W2r + (size_t)(g * 2) * 36 * 64 + lane;
    const u64* a1p = a0p + 36 * 64;

    f32x16 acc00 = {}, acc10 = {}, acc01 = {}, acc11 = {};  // acc[oh][NT]
    u64 A0[4], A1[4];
    A0[0] = a0p[0];   A1[0] = a1p[0];
    A0[1] = a0p[64];  A1[1] = a1p[64];
    A0[2] = a0p[128]; A1[2] = a1p[128];

#pragma unroll
    for (int tap = 0; tap < 9; ++tap) {
        const int D = (tap / 3) * 18 + (tap % 3);
        int p0 = baseNT0 + D;
        int p1 = baseNT1 + D;
        int X0 = (p0 & 7) ^ ((p0 >> 3) & 3);
        int X1 = (p1 & 7) ^ ((p1 >> 3) & 3);
        int ad0 = (p0 << 6) + ((hi ^ X0) << 3);
        int ad1 = (p1 << 6) + ((hi ^ X1) << 3);
#pragma unroll
        for (int q = 0; q < 4; ++q) {
            const int kk = tap * 4 + q;
            if (kk + 3 < 36) {
                A0[(kk + 3) & 3] = a0p[(kk + 3) * 64];
                A1[(kk + 3) & 3] = a1p[(kk + 3) * 64];
            }
            u64 bf0  = *(const u64*)(h1c + (ad0 ^ (q << 4)));
            u64 bf1v = *(const u64*)(h1c + (ad1 ^ (q << 4)));
            acc00 = __builtin_amdgcn_mfma_f32_32x32x16_fp8_fp8((long)A0[kk & 3], (long)bf0,  acc00, 0, 0, 0);
            acc10 = __builtin_amdgcn_mfma_f32_32x32x16_fp8_fp8((long)A1[kk & 3], (long)bf0,  acc10, 0, 0, 0);
            acc01 = __builtin_amdgcn_mfma_f32_32x32x16_fp8_fp8((long)A0[kk & 3], (long)bf1v, acc01, 0, 0, 0);
            acc11 = __builtin_amdgcn_mfma_f32_32x32x16_fp8_fp8((long)A1[kk & 3], (long)bf1v, acc11, 0, 0, 0);
        }
    }

    // ---- epilogue (oh-sequential to cap regs): gelu(+b2), dot W3, reduce, store
    float p0 = 0.f, p1 = 0.f;
#pragma unroll
    for (int oh = 0; oh < 2; ++oh) {
        float w3r[16], b2r[16];
        const float* wp = W3 + g * 64 + oh * 32 + 4 * hi;
        const float* bp = b2 + g * 64 + oh * 32 + 4 * hi;
#pragma unroll
        for (int s = 0; s < 4; ++s) {
            float4 qa = *(const float4*)(wp + 8 * s);
            float4 qb = *(const float4*)(bp + 8 * s);
            w3r[4 * s + 0] = qa.x; w3r[4 * s + 1] = qa.y;
            w3r[4 * s + 2] = qa.z; w3r[4 * s + 3] = qa.w;
            b2r[4 * s + 0] = qb.x; b2r[4 * s + 1] = qb.y;
            b2r[4 * s + 2] = qb.z; b2r[4 * s + 3] = qb.w;
        }
        f32x16 AN0 = oh ? acc10 : acc00;
        f32x16 AN1 = oh ? acc11 : acc01;
#pragma unroll
        for (int r = 0; r < 16; ++r) {
            p0 = __builtin_fmaf(w3r[r], gelu_f(AN0[r] + b2r[r]), p0);
            p1 = __builtin_fmaf(w3r[r], gelu_f(AN1[r] + b2r[r]), p1);
        }
    }
    p0 += __shfl_xor(p0, 32);
    p1 += __shfl_xor(p1, 32);
    const float b3g = b3[g];
    float* outg = out + ((size_t)(n * NB + g) * 192 + y0) * 192 + x0;
    if (lane < 32) {
        int py0 = w * 4 + (lane >> 4);
        outg[py0 * 192 + (lane & 15)] = p0 + b3g;
        outg[(py0 + 2) * 192 + (lane & 15)] = p1 + b3g;
    }
}

// Cross-band fusion, in-place on `out`. Wave handles 32 pixel-columns;
// lane halves split the 62-wide j loop, combined via shfl_xor(32).
__global__ __launch_bounds__(256) void fuse_kernel(
    const float* __restrict__ x,
    const float* __restrict__ Wf1, const float* __restrict__ bf1,
    const float* __restrict__ Wf2, const float* __restrict__ bf2,
    float* __restrict__ out)
{
    const int tid  = threadIdx.x;
    const int lane = tid & 63;
    const int jh   = lane >> 5;                       // j-half: 0 -> 0..30, 1 -> 31..61
    int wv = (blockIdx.x * 256 + tid) >> 6;           // 0..2303
    int p  = wv * 32 + (lane & 31);                   // pixel-column id, 0..73727
    int nn = p / 36864, pix = p - nn * 36864;
    float* basep = out + (size_t)nn * NB * 36864 + pix;
    const float* xb = x + (size_t)nn * NB * 36864 + pix;

    float v[31];
#pragma unroll
    for (int c = 0; c < 31; ++c) v[c] = basep[(size_t)c * 36864];

    float fused[31];
#pragma unroll
    for (int c = 0; c < 31; ++c) fused[c] = 0.f;

    for (int jj = 0; jj < 31; ++jj) {
        int j = jh * 31 + jj;
        float a = bf1[j];
#pragma unroll
        for (int c = 0; c < 31; ++c) a = __builtin_fmaf(Wf1[j * 31 + c], v[c], a);
        float fj = gelu_f(a);
#pragma unroll
        for (int c = 0; c < 31; ++c) fused[c] = __builtin_fmaf(Wf2[c * 62 + j], fj, fused[c]);
    }
#pragma unroll
    for (int c = 0; c < 31; ++c) fused[c] += __shfl_xor(fused[c], 32);
    if (jh == 0) {
#pragma unroll
        for (int c = 0; c < 31; ++c)
            basep[(size_t)c * 36864] = xb[(size_t)c * 36864] + fused[c] + bf2[c];
    }
}

extern "C" void kernel_launch(void* const* d_in, const int* in_sizes, int n_in,
                              void* d_out, int out_size, void* d_ws, size_t ws_size,
                              hipStream_t stream) {
    const float* x   = (const float*)d_in[0];
    const float* W1  = (const float*)d_in[1];
    const float* b1  = (const float*)d_in[2];
    const float* W2  = (const float*)d_in[3];
    const float* b2  = (const float*)d_in[4];
    const float* W3  = (const float*)d_in[5];
    const float* b3  = (const float*)d_in[6];
    const float* Wf1 = (const float*)d_in[7];
    const float* bf1 = (const float*)d_in[8];
    const float* Wf2 = (const float*)d_in[9];
    const float* bf2 = (const float*)d_in[10];
    float* out = (float*)d_out;
    unsigned char* W2r = (unsigned char*)d_ws;   // 1,142,784 B fp8 fragments

    const int TOT = NB * 2 * 36 * 64;
    hipLaunchKernelGGL(prep_w2, dim3((TOT + 255) / 256), dim3(256), 0, stream, W2, W2r);
    hipLaunchKernelGGL(band_kernel, dim3(144, NB, 2), dim3(256), 0, stream,
                       x, W1, b1, b2, W3, b3, W2r, out);
    hipLaunchKernelGGL(fuse_kernel, dim3(576), dim3(256), 0, stream,
                       x, Wf1, bf1, Wf2, bf2, out);
}

// Round 9
// 214.201 us; speedup vs baseline: 1.1753x; 1.0568x over previous
//
#include <hip/hip_runtime.h>
#include <hip/hip_bf16.h>

#define NB 31
#define PD 64

typedef __attribute__((ext_vector_type(8))) short short8;
typedef __attribute__((ext_vector_type(16))) float f32x16;
typedef unsigned long long u64;

// 4-inst GELU core: x * clamp(0.5 + x*(a + b x^2 + c x^4), 0, 1) via VOP3 clamp
__device__ __forceinline__ float gelu_f(float x) {
    float y = x * x;
    float p = __builtin_fmaf(y, __builtin_fmaf(y, 0.0042294f, -0.056913f), 0.395442f);
    float phi;
    asm("v_fma_f32 %0, %1, %2, 0.5 clamp" : "=v"(phi) : "v"(x), "v"(p));
    return x * phi;
}

__device__ __forceinline__ unsigned int cvt_pk_bf16(float lo, float hi) {
    unsigned int r;
    asm("v_cvt_pk_bf16_f32 %0, %1, %2" : "=v"(r) : "v"(lo), "v"(hi));
    return r;
}

// 2 floats -> 2 fp8 e4m3 bytes in bits [15:0] (old=0 => high bits are 0)
__device__ __forceinline__ unsigned int pk_fp8(float a, float b) {
    return (unsigned int)__builtin_amdgcn_cvt_pk_fp8_f32(a, b, 0, false);
}

// Reorder W2 (OIHW, fp32) -> fp8 e4m3 MFMA A-fragment order:
// W2r[g][oh][kk][lane] = 8 bytes, oc = oh*32 + (lane&31), tap = kk>>2,
// ic = (kk&3)*16 + (lane>>5)*8 + j
__global__ void prep_w2(const float* __restrict__ W2, unsigned char* __restrict__ W2r) {
    int e = blockIdx.x * 256 + threadIdx.x;
    const int TOT = NB * 2 * 36 * 64;
    if (e >= TOT) return;
    int lane = e & 63;
    int kk = (e >> 6) % 36;
    int gh = e / (36 * 64);
    int g = gh >> 1, oh = gh & 1;
    int oc  = oh * 32 + (lane & 31);
    int icb = (kk & 3) * 16 + ((lane >> 5) << 3);
    int tap = kk >> 2;
    const float* wp = W2 + ((size_t)(g * 64 + oc) * 64 + icb) * 9 + tap;
    float f[8];
#pragma unroll
    for (int j = 0; j < 8; ++j) f[j] = wp[j * 9];
    uint2 st;
    st.x = pk_fp8(f[0], f[1]) | (pk_fp8(f[2], f[3]) << 16);
    st.y = pk_fp8(f[4], f[5]) | (pk_fp8(f[6], f[7]) << 16);
    ((uint2*)W2r)[e] = st;
}

// One block: (batch n, band g, 16x16 tile). 512 threads = 8 waves = (oh, w4).
// Wave handles its oc-half only: conv2 accs = 2 (32 AGPR) -> 6 waves/SIMD.
// b1 folded into conv1 K-pad (k=9, B=1.0); b2 folded into conv2 acc C-init.
__global__ __launch_bounds__(512, 6) void band_kernel(
    const float* __restrict__ x, const float* __restrict__ W1, const float* __restrict__ b1,
    const float* __restrict__ b2, const float* __restrict__ W3, const float* __restrict__ b3,
    const unsigned char* __restrict__ W2r, float* __restrict__ out)
{
    __shared__ float xs[20 * 20];
    __shared__ u64   h1s8[352 * 8];   // 22528 B: rows 0..351 (324 real)
    __shared__ float outs[2 * 256];

    const int tid = threadIdx.x;
    const int tx = blockIdx.x % 12, ty = blockIdx.x / 12;
    const int g = blockIdx.y, n = blockIdx.z;
    const int x0 = tx * 16, y0 = ty * 16;

    const int lane = tid & 63;
    const int wid  = tid >> 6;
    const int w4   = wid & 3;       // row-quarter
    const int oh   = wid >> 2;      // oc-half
    const int hi   = lane >> 5;     // k-half for MFMA operands
    const int col  = lane & 31;

    // ---- stage x tile (20x20, halo 2, zero-padded) ----
    const float* xg = x + (size_t)(n * NB + g) * 192 * 192;
    if (tid < 400) {
        int r = tid / 20, c = tid - r * 20;
        int gy = y0 + r - 2, gx = x0 + c - 2;
        float v = 0.f;
        if (gy >= 0 && gy < 192 && gx >= 0 && gx < 192) v = xg[gy * 192 + gx];
        xs[tid] = v;
    }

    // ---- conv1 A-frag (this wave's oh only): k=tap 0..8, k=9 -> b1[oc] ----
    short8 a1;
    {
        const float* wp = W1 + (size_t)(g * 64 + oh * 32 + col) * 9;
        uint4 bw = {0u, 0u, 0u, 0u};
        if (hi == 0) {
            bw.x = cvt_pk_bf16(wp[0], wp[1]);
            bw.y = cvt_pk_bf16(wp[2], wp[3]);
            bw.z = cvt_pk_bf16(wp[4], wp[5]);
            bw.w = cvt_pk_bf16(wp[6], wp[7]);
        } else {
            bw.x = cvt_pk_bf16(wp[8], b1[g * 64 + oh * 32 + col]);
        }
        a1 = __builtin_bit_cast(short8, bw);
    }
    __syncthreads();   // xs ready

    // ---- conv1 via MFMA: 11 tiles of 32 positions; wave (oh,w4) -> t=w4+4it
    char* h1c = (char*)h1s8;
#pragma unroll
    for (int it = 0; it < 3; ++it) {
        const int t = w4 + 4 * it;
        if (t < 11) {
            const int posr = t * 32 + col;             // write row 0..351
            const int pos  = posr < 324 ? posr : 323;  // compute pos (in-bounds)
            int py = pos / 18, px = pos - py * 18;
            int gy = y0 + py - 1, gx = x0 + px - 1;
            unsigned int msk = (gy >= 0 && gy < 192 && gx >= 0 && gx < 192) ? 0xFFFFFFFFu : 0u;

            // B frag: lanes<32: taps 0..7; lanes>=32: k8=center tap, k9=1.0 (bias)
            uint4 bw = {0u, 0u, 0u, 0u};
            if (hi == 0) {
                float xv[8];
#pragma unroll
                for (int j2 = 0; j2 < 8; ++j2)
                    xv[j2] = xs[(py + j2 / 3) * 20 + px + (j2 % 3)];
                bw.x = cvt_pk_bf16(xv[0], xv[1]);
                bw.y = cvt_pk_bf16(xv[2], xv[3]);
                bw.z = cvt_pk_bf16(xv[4], xv[5]);
                bw.w = cvt_pk_bf16(xv[6], xv[7]);
            } else {
                bw.x = cvt_pk_bf16(xs[(py + 2) * 20 + px + 2], 1.0f);
            }
            short8 bfrag = __builtin_bit_cast(short8, bw);

            f32x16 z = {};
            f32x16 c0 = __builtin_amdgcn_mfma_f32_32x32x16_bf16(a1, bfrag, z, 0, 0, 0);

            // gelu -> fp8 -> per-lane 4B stores.  chunk = oh*4+s, half = hi.
            const int X = (posr & 7) ^ ((posr >> 3) & 3);
            const int rowb = (posr << 6) + (hi << 2);
#pragma unroll
            for (int s = 0; s < 4; ++s) {
                float u0 = gelu_f(c0[4 * s + 0]);
                float u1 = gelu_f(c0[4 * s + 1]);
                float u2 = gelu_f(c0[4 * s + 2]);
                float u3 = gelu_f(c0[4 * s + 3]);
                unsigned int E = (pk_fp8(u0, u1) | (pk_fp8(u2, u3) << 16)) & msk;
                *(unsigned int*)(h1c + rowb + ((((oh << 2) | s) ^ X) << 3)) = E;
            }
        }
    }
    __syncthreads();

    // ---- conv2 via fp8 MFMA: wave (oh,w4) = px rows [4w4,4w4+4) x its 32 oc
    const int lhalf = (lane >> 4) & 1;
    const int pxl   = lane & 15;
    const int base0 = (4 * w4 + lhalf) * 18 + pxl;
    const int base1 = base0 + 36;

    const u64* ap = (const u64*)W2r + (size_t)(g * 2 + oh) * 36 * 64 + lane;

    // acc C-init = b2 (broadcast over columns; same for NT0/NT1)
    f32x16 acc0, acc1;
    {
        const float* bp = b2 + g * 64 + oh * 32 + 4 * hi;
#pragma unroll
        for (int s = 0; s < 4; ++s) {
            float4 q = *(const float4*)(bp + 8 * s);
            acc0[4 * s + 0] = q.x; acc0[4 * s + 1] = q.y;
            acc0[4 * s + 2] = q.z; acc0[4 * s + 3] = q.w;
            acc1[4 * s + 0] = q.x; acc1[4 * s + 1] = q.y;
            acc1[4 * s + 2] = q.z; acc1[4 * s + 3] = q.w;
        }
    }

    u64 A[4];
    A[0] = ap[0]; A[1] = ap[64]; A[2] = ap[128];

#pragma unroll
    for (int tap = 0; tap < 9; ++tap) {
        const int D = (tap / 3) * 18 + (tap % 3);
        int p0 = base0 + D;
        int p1 = base1 + D;
        int X0 = (p0 & 7) ^ ((p0 >> 3) & 3);
        int X1 = (p1 & 7) ^ ((p1 >> 3) & 3);
        int ad0 = (p0 << 6) + ((hi ^ X0) << 3);
        int ad1 = (p1 << 6) + ((hi ^ X1) << 3);
#pragma unroll
        for (int q = 0; q < 4; ++q) {
            const int kk = tap * 4 + q;
            if (kk + 3 < 36) A[(kk + 3) & 3] = ap[(kk + 3) * 64];
            u64 bf0 = *(const u64*)(h1c + (ad0 ^ (q << 4)));
            u64 bf1 = *(const u64*)(h1c + (ad1 ^ (q << 4)));
            acc0 = __builtin_amdgcn_mfma_f32_32x32x16_fp8_fp8((long)A[kk & 3], (long)bf0, acc0, 0, 0, 0);
            acc1 = __builtin_amdgcn_mfma_f32_32x32x16_fp8_fp8((long)A[kk & 3], (long)bf1, acc1, 0, 0, 0);
        }
    }

    // ---- epilogue: gelu, dot W3 (this oh), k-half reduce, cross-oh via LDS
    float pa = 0.f, pb = 0.f;
    {
        const float* wp3 = W3 + g * 64 + oh * 32 + 4 * hi;
#pragma unroll
        for (int s = 0; s < 4; ++s) {
            float4 qa = *(const float4*)(wp3 + 8 * s);
            pa = __builtin_fmaf(qa.x, gelu_f(acc0[4 * s + 0]), pa);
            pa = __builtin_fmaf(qa.y, gelu_f(acc0[4 * s + 1]), pa);
            pa = __builtin_fmaf(qa.z, gelu_f(acc0[4 * s + 2]), pa);
            pa = __builtin_fmaf(qa.w, gelu_f(acc0[4 * s + 3]), pa);
            pb = __builtin_fmaf(qa.x, gelu_f(acc1[4 * s + 0]), pb);
            pb = __builtin_fmaf(qa.y, gelu_f(acc1[4 * s + 1]), pb);
            pb = __builtin_fmaf(qa.z, gelu_f(acc1[4 * s + 2]), pb);
            pb = __builtin_fmaf(qa.w, gelu_f(acc1[4 * s + 3]), pb);
        }
    }
    pa += __shfl_xor(pa, 32);
    pb += __shfl_xor(pb, 32);
    if (lane < 32) {
        outs[oh * 256 + w4 * 64 + lane]      = pa;   // NT0 cols
        outs[oh * 256 + w4 * 64 + 32 + lane] = pb;   // NT1 cols
    }
    __syncthreads();

    if (tid < 256) {
        float v = outs[tid] + outs[256 + tid] + b3[g];
        int py = 4 * (tid >> 6) + 2 * ((tid >> 5) & 1) + ((tid >> 4) & 1);
        int px = tid & 15;
        out[((size_t)(n * NB + g) * 192 + y0 + py) * 192 + x0 + px] = v;
    }
}

// Cross-band fusion, in-place on `out`. Thread owns one pixel column;
// j is wave-uniform -> weights via s_load (K$/L2), no LDS.
__global__ __launch_bounds__(256) void fuse_kernel(
    const float* __restrict__ x,
    const float* __restrict__ Wf1, const float* __restrict__ bf1,
    const float* __restrict__ Wf2, const float* __restrict__ bf2,
    float* __restrict__ out)
{
    const int tid = threadIdx.x;
    int p = blockIdx.x * 256 + tid;          // 0..73727
    int nn = p / 36864, pix = p - nn * 36864;
    float* basep = out + (size_t)nn * NB * 36864 + pix;
    const float* xb = x + (size_t)nn * NB * 36864 + pix;

    float v[31];
#pragma unroll
    for (int c = 0; c < 31; ++c) v[c] = basep[(size_t)c * 36864];

    float fused[31];
#pragma unroll
    for (int c = 0; c < 31; ++c) fused[c] = bf2[c];

#pragma unroll 2
    for (int j = 0; j < 62; ++j) {
        float a = bf1[j];
#pragma unroll
        for (int c = 0; c < 31; ++c) a = __builtin_fmaf(Wf1[j * 31 + c], v[c], a);
        float fj = gelu_f(a);
#pragma unroll
        for (int c = 0; c < 31; ++c) fused[c] = __builtin_fmaf(Wf2[c * 62 + j], fj, fused[c]);
    }
#pragma unroll
    for (int c = 0; c < 31; ++c) basep[(size_t)c * 36864] = xb[(size_t)c * 36864] + fused[c];
}

extern "C" void kernel_launch(void* const* d_in, const int* in_sizes, int n_in,
                              void* d_out, int out_size, void* d_ws, size_t ws_size,
                              hipStream_t stream) {
    const float* x   = (const float*)d_in[0];
    const float* W1  = (const float*)d_in[1];
    const float* b1  = (const float*)d_in[2];
    const float* W2  = (const float*)d_in[3];
    const float* b2  = (const float*)d_in[4];
    const float* W3  = (const float*)d_in[5];
    const float* b3  = (const float*)d_in[6];
    const float* Wf1 = (const float*)d_in[7];
    const float* bf1 = (const float*)d_in[8];
    const float* Wf2 = (const float*)d_in[9];
    const float* bf2 = (const float*)d_in[10];
    float* out = (float*)d_out;
    unsigned char* W2r = (unsigned char*)d_ws;   // 571,392 B fp8 fragments

    const int TOT = NB * 2 * 36 * 64;
    hipLaunchKernelGGL(prep_w2, dim3((TOT + 255) / 256), dim3(256), 0, stream, W2, W2r);
    hipLaunchKernelGGL(band_kernel, dim3(144, NB, 2), dim3(512), 0, stream,
                       x, W1, b1, b2, W3, b3, W2r, out);
    hipLaunchKernelGGL(fuse_kernel, dim3(288), dim3(256), 0, stream,
                       x, Wf1, bf1, Wf2, bf2, out);
}

// Round 10
// 184.123 us; speedup vs baseline: 1.3673x; 1.1634x over previous
//
#include <hip/hip_runtime.h>
#include <hip/hip_bf16.h>

#define NB 31
#define PD 64

typedef __attribute__((ext_vector_type(8))) short short8;
typedef __attribute__((ext_vector_type(16))) float f32x16;
typedef __attribute__((ext_vector_type(8))) int int8v;

// 4-inst GELU: x * clamp(0.5 + x*(a + b x^2 + c x^4), 0, 1) via VOP3 clamp
__device__ __forceinline__ float gelu_f(float x) {
    float y = x * x;
    float p = __builtin_fmaf(y, __builtin_fmaf(y, 0.0042294f, -0.056913f), 0.395442f);
    float phi;
    asm("v_fma_f32 %0, %1, %2, 0.5 clamp" : "=v"(phi) : "v"(x), "v"(p));
    return x * phi;
}

__device__ __forceinline__ unsigned int cvt_pk_bf16(float lo, float hi) {
    unsigned int r;
    asm("v_cvt_pk_bf16_f32 %0, %1, %2" : "=v"(r) : "v"(lo), "v"(hi));
    return r;
}

// 2 floats -> 2 fp8 e4m3 bytes in bits [15:0] (old=0 => high bits 0)
__device__ __forceinline__ unsigned int pk_fp8(float a, float b) {
    return (unsigned int)__builtin_amdgcn_cvt_pk_fp8_f32(a, b, 0, false);
}

__device__ __forceinline__ int8v mk8(uint4 a, uint4 b) {
    int8v r;
    r[0] = a.x; r[1] = a.y; r[2] = a.z; r[3] = a.w;
    r[4] = b.x; r[5] = b.y; r[6] = b.z; r[7] = b.w;
    return r;
}

// W2 (OIHW fp32) -> fp8 MX-MFMA A-fragments for 32x32x64:
// W2s[gh][tap][lane] = 32 bytes; gh = g*2+oh; lane = hi*32 + col (col = oc-31);
// byte b (0..31) = fp8(W2[g*64+oh*32+col][ic = hi*32 + b][tap])
__global__ void prep_w2(const float* __restrict__ W2, unsigned char* __restrict__ W2s) {
    int e = blockIdx.x * 256 + threadIdx.x;
    const int TOT = NB * 2 * 9 * 64;
    if (e >= TOT) return;
    int lane = e & 63;
    int tap  = (e >> 6) % 9;
    int gh   = e / (9 * 64);
    int g = gh >> 1, oh = gh & 1;
    int col = lane & 31, hi = lane >> 5;
    const float* wp = W2 + ((size_t)(g * 64 + oh * 32 + col) * 64 + hi * 32) * 9 + tap;
    uint4 q0, q1;
    unsigned int d[8];
#pragma unroll
    for (int i = 0; i < 8; ++i) {
        float f0 = wp[(4 * i + 0) * 9];
        float f1 = wp[(4 * i + 1) * 9];
        float f2 = wp[(4 * i + 2) * 9];
        float f3 = wp[(4 * i + 3) * 9];
        d[i] = pk_fp8(f0, f1) | (pk_fp8(f2, f3) << 16);
    }
    q0.x = d[0]; q0.y = d[1]; q0.z = d[2]; q0.w = d[3];
    q1.x = d[4]; q1.y = d[5]; q1.z = d[6]; q1.w = d[7];
    uint4* op = (uint4*)W2s + (size_t)e * 2;
    op[0] = q0; op[1] = q1;
}

// One block: (batch n, band g, 16x16 tile). 512 threads = 8 waves = (oh, w4).
// conv1 bf16 MFMA -> h1 fp8 in LDS (16B-slot swizzled) -> conv2 via
// mfma_scale_f32_32x32x64_f8f6f4 (scale = 1.0): 18 MFMAs/wave, K=64/instr.
// LDS row (pos) = 64B; ic-chunk c (0..3) at slot bitrev2(c) ^ (pos&3).
__global__ __launch_bounds__(512, 5) void band_kernel(
    const float* __restrict__ x, const float* __restrict__ W1, const float* __restrict__ b1,
    const float* __restrict__ b2, const float* __restrict__ W3, const float* __restrict__ b3,
    const unsigned char* __restrict__ W2s, float* __restrict__ out)
{
    __shared__ float xs[20 * 20];
    __shared__ uint4 h1s[352 * 4];   // 22528 B: [pos][4 x 16B slots]
    __shared__ float outs[2 * 256];

    const int tid = threadIdx.x;
    const int tx = blockIdx.x % 12, ty = blockIdx.x / 12;
    const int g = blockIdx.y, n = blockIdx.z;
    const int x0 = tx * 16, y0 = ty * 16;

    const int lane = tid & 63;
    const int wid  = tid >> 6;
    const int w4   = wid & 3;       // row-quarter
    const int oh   = wid >> 2;      // oc-half
    const int hi   = lane >> 5;     // k-half
    const int col  = lane & 31;

    // ---- stage x tile (20x20, halo 2, zero-padded) ----
    const float* xg = x + (size_t)(n * NB + g) * 192 * 192;
    if (tid < 400) {
        int r = tid / 20, c = tid - r * 20;
        int gy = y0 + r - 2, gx = x0 + c - 2;
        float v = 0.f;
        if (gy >= 0 && gy < 192 && gx >= 0 && gx < 192) v = xg[gy * 192 + gx];
        xs[tid] = v;
    }

    // ---- conv1 A-frag (this wave's oh): k=tap 0..8, k=9 -> b1[oc] ----
    short8 a1;
    {
        const float* wp = W1 + (size_t)(g * 64 + oh * 32 + col) * 9;
        uint4 bw = {0u, 0u, 0u, 0u};
        if (hi == 0) {
            bw.x = cvt_pk_bf16(wp[0], wp[1]);
            bw.y = cvt_pk_bf16(wp[2], wp[3]);
            bw.z = cvt_pk_bf16(wp[4], wp[5]);
            bw.w = cvt_pk_bf16(wp[6], wp[7]);
        } else {
            bw.x = cvt_pk_bf16(wp[8], b1[g * 64 + oh * 32 + col]);
        }
        a1 = __builtin_bit_cast(short8, bw);
    }
    __syncthreads();   // xs ready

    // ---- conv1 via MFMA: 11 tiles of 32 positions ----
    char* h1c = (char*)h1s;
#pragma unroll
    for (int it = 0; it < 3; ++it) {
        const int t = w4 + 4 * it;
        if (t < 11) {
            const int posr = t * 32 + col;             // write row 0..351
            const int pos  = posr < 324 ? posr : 323;  // compute pos (in-bounds)
            int py = pos / 18, px = pos - py * 18;
            int gy = y0 + py - 1, gx = x0 + px - 1;
            unsigned int msk = (gy >= 0 && gy < 192 && gx >= 0 && gx < 192) ? 0xFFFFFFFFu : 0u;

            uint4 bw = {0u, 0u, 0u, 0u};
            if (hi == 0) {
                float xv[8];
#pragma unroll
                for (int j2 = 0; j2 < 8; ++j2)
                    xv[j2] = xs[(py + j2 / 3) * 20 + px + (j2 % 3)];
                bw.x = cvt_pk_bf16(xv[0], xv[1]);
                bw.y = cvt_pk_bf16(xv[2], xv[3]);
                bw.z = cvt_pk_bf16(xv[4], xv[5]);
                bw.w = cvt_pk_bf16(xv[6], xv[7]);
            } else {
                bw.x = cvt_pk_bf16(xs[(py + 2) * 20 + px + 2], 1.0f);
            }
            short8 bfrag = __builtin_bit_cast(short8, bw);

            f32x16 z = {};
            f32x16 c0 = __builtin_amdgcn_mfma_f32_32x32x16_bf16(a1, bfrag, z, 0, 0, 0);

            // gelu -> fp8 -> 4B stores. acc reg 4s+j -> ic = oh*32 + 8s + 4hi + j.
            // chunk c = 2oh + (s>>1); slot = bitrev2(c)^ (posr&3) = ((s&2)|oh)^(posr&3);
            // byte-in-slot = 8(s&1) + 4hi.
            const int rowb = posr << 6;
            const int sw = posr & 3;
#pragma unroll
            for (int s = 0; s < 4; ++s) {
                float u0 = gelu_f(c0[4 * s + 0]);
                float u1 = gelu_f(c0[4 * s + 1]);
                float u2 = gelu_f(c0[4 * s + 2]);
                float u3 = gelu_f(c0[4 * s + 3]);
                unsigned int E = (pk_fp8(u0, u1) | (pk_fp8(u2, u3) << 16)) & msk;
                int slot = ((s & 2) | oh) ^ sw;
                *(unsigned int*)(h1c + rowb + (slot << 4) + ((s & 1) << 3) + (hi << 2)) = E;
            }
        }
    }
    __syncthreads();

    // ---- conv2 via MX fp8 MFMA: wave (oh,w4) = px rows [4w4,4w4+4) x 32 oc
    const int lhalf = (lane >> 4) & 1;
    const int pxl   = lane & 15;
    const int base0 = (4 * w4 + lhalf) * 18 + pxl;

    const int gh = g * 2 + oh;
    const uint4* ap = (const uint4*)W2s + (size_t)gh * 9 * 128 + lane * 2;

    // acc C-init = b2 (broadcast over columns)
    f32x16 acc0, acc1;
    {
        const float* bp = b2 + g * 64 + oh * 32 + 4 * hi;
#pragma unroll
        for (int s = 0; s < 4; ++s) {
            float4 q = *(const float4*)(bp + 8 * s);
            acc0[4 * s + 0] = q.x; acc0[4 * s + 1] = q.y;
            acc0[4 * s + 2] = q.z; acc0[4 * s + 3] = q.w;
            acc1[4 * s + 0] = q.x; acc1[4 * s + 1] = q.y;
            acc1[4 * s + 2] = q.z; acc1[4 * s + 3] = q.w;
        }
    }

    // A ring: prefetch distance 2 taps
    uint4 Aq[3][2];
    Aq[0][0] = ap[0];   Aq[0][1] = ap[1];
    Aq[1][0] = ap[128]; Aq[1][1] = ap[129];

#pragma unroll
    for (int tap = 0; tap < 9; ++tap) {
        if (tap + 2 < 9) {
            Aq[(tap + 2) % 3][0] = ap[(tap + 2) * 128];
            Aq[(tap + 2) % 3][1] = ap[(tap + 2) * 128 + 1];
        }
        const int D = (tap / 3) * 18 + (tap % 3);
        const int p0 = base0 + D;
        const int p1 = p0 + 36;
        const uint4* r0 = (const uint4*)(h1c + (p0 << 6));
        const uint4* r1 = (const uint4*)(h1c + (p1 << 6));
        const int s0 = p0 & 3, s1 = p1 & 3;
        // lane reads ic [32hi, 32hi+32): chunks 2hi, 2hi+1 -> slots hi^sw, (2|hi)^sw
        uint4 b0a = r0[hi ^ s0];
        uint4 b0b = r0[(2 | hi) ^ s0];
        uint4 b1a = r1[hi ^ s1];
        uint4 b1b = r1[(2 | hi) ^ s1];
        int8v A = mk8(Aq[tap % 3][0], Aq[tap % 3][1]);
        acc0 = __builtin_amdgcn_mfma_scale_f32_32x32x64_f8f6f4(
                   A, mk8(b0a, b0b), acc0, 0, 0, 0, 0x7F7F7F7F, 0, 0x7F7F7F7F);
        acc1 = __builtin_amdgcn_mfma_scale_f32_32x32x64_f8f6f4(
                   A, mk8(b1a, b1b), acc1, 0, 0, 0, 0x7F7F7F7F, 0, 0x7F7F7F7F);
    }

    // ---- epilogue: gelu, dot W3 (this oh), k-half reduce, cross-oh via LDS
    float pa = 0.f, pb = 0.f;
    {
        const float* wp3 = W3 + g * 64 + oh * 32 + 4 * hi;
#pragma unroll
        for (int s = 0; s < 4; ++s) {
            float4 qa = *(const float4*)(wp3 + 8 * s);
            pa = __builtin_fmaf(qa.x, gelu_f(acc0[4 * s + 0]), pa);
            pa = __builtin_fmaf(qa.y, gelu_f(acc0[4 * s + 1]), pa);
            pa = __builtin_fmaf(qa.z, gelu_f(acc0[4 * s + 2]), pa);
            pa = __builtin_fmaf(qa.w, gelu_f(acc0[4 * s + 3]), pa);
            pb = __builtin_fmaf(qa.x, gelu_f(acc1[4 * s + 0]), pb);
            pb = __builtin_fmaf(qa.y, gelu_f(acc1[4 * s + 1]), pb);
            pb = __builtin_fmaf(qa.z, gelu_f(acc1[4 * s + 2]), pb);
            pb = __builtin_fmaf(qa.w, gelu_f(acc1[4 * s + 3]), pb);
        }
    }
    pa += __shfl_xor(pa, 32);
    pb += __shfl_xor(pb, 32);
    if (lane < 32) {
        outs[oh * 256 + w4 * 64 + lane]      = pa;   // NT0
        outs[oh * 256 + w4 * 64 + 32 + lane] = pb;   // NT1
    }
    __syncthreads();

    if (tid < 256) {
        float v = outs[tid] + outs[256 + tid] + b3[g];
        int py = 4 * (tid >> 6) + 2 * ((tid >> 5) & 1) + ((tid >> 4) & 1);
        int px = tid & 15;
        out[((size_t)(n * NB + g) * 192 + y0 + py) * 192 + x0 + px] = v;
    }
}

// Cross-band fusion, in-place on `out`. Thread owns one pixel column;
// j is wave-uniform -> weights via s_load (K$/L2), no LDS.
__global__ __launch_bounds__(256) void fuse_kernel(
    const float* __restrict__ x,
    const float* __restrict__ Wf1, const float* __restrict__ bf1,
    const float* __restrict__ Wf2, const float* __restrict__ bf2,
    float* __restrict__ out)
{
    const int tid = threadIdx.x;
    int p = blockIdx.x * 256 + tid;          // 0..73727
    int nn = p / 36864, pix = p - nn * 36864;
    float* basep = out + (size_t)nn * NB * 36864 + pix;
    const float* xb = x + (size_t)nn * NB * 36864 + pix;

    float v[31];
#pragma unroll
    for (int c = 0; c < 31; ++c) v[c] = basep[(size_t)c * 36864];

    float fused[31];
#pragma unroll
    for (int c = 0; c < 31; ++c) fused[c] = bf2[c];

#pragma unroll 2
    for (int j = 0; j < 62; ++j) {
        float a = bf1[j];
#pragma unroll
        for (int c = 0; c < 31; ++c) a = __builtin_fmaf(Wf1[j * 31 + c], v[c], a);
        float fj = gelu_f(a);
#pragma unroll
        for (int c = 0; c < 31; ++c) fused[c] = __builtin_fmaf(Wf2[c * 62 + j], fj, fused[c]);
    }
#pragma unroll
    for (int c = 0; c < 31; ++c) basep[(size_t)c * 36864] = xb[(size_t)c * 36864] + fused[c];
}

extern "C" void kernel_launch(void* const* d_in, const int* in_sizes, int n_in,
                              void* d_out, int out_size, void* d_ws, size_t ws_size,
                              hipStream_t stream) {
    const float* x   = (const float*)d_in[0];
    const float* W1  = (const float*)d_in[1];
    const float* b1  = (const float*)d_in[2];
    const float* W2  = (const float*)d_in[3];
    const float* b2  = (const float*)d_in[4];
    const float* W3  = (const float*)d_in[5];
    const float* b3  = (const float*)d_in[6];
    const float* Wf1 = (const float*)d_in[7];
    const float* bf1 = (const float*)d_in[8];
    const float* Wf2 = (const float*)d_in[9];
    const float* bf2 = (const float*)d_in[10];
    float* out = (float*)d_out;
    unsigned char* W2s = (unsigned char*)d_ws;   // 62*9*64*32 = 1,142,784 B

    const int TOT = NB * 2 * 9 * 64;
    hipLaunchKernelGGL(prep_w2, dim3((TOT + 255) / 256), dim3(256), 0, stream, W2, W2s);
    hipLaunchKernelGGL(band_kernel, dim3(144, NB, 2), dim3(512), 0, stream,
                       x, W1, b1, b2, W3, b3, W2s, out);
    hipLaunchKernelGGL(fuse_kernel, dim3(288), dim3(256), 0, stream,
                       x, Wf1, bf1, Wf2, bf2, out);
}